// Round 11
// baseline (190.761 us; speedup 1.0000x reference)
//
#include <hip/hip_runtime.h>
#include <math.h>

#define ALPHA   0.99f
#define ONE_M   0.01f     // 1 - ALPHA
#define T_LEN   4000
#define F_DIM   64
#define TT      400       // time rows per tile
#define NTILE   10        // T_LEN / TT
#define LTC     10        // chunk length (rows per chunk)
#define NC      40        // chunks per tile = TT / LTC
#define NPC     10        // coop pieces per thread = TT*F_DIM/(NTHREADS*4)
#define NTHREADS 640      // 10 waves
#define ROWF    68        // LDS image row stride in floats (272 B)

typedef float f32x4 __attribute__((ext_vector_type(4)));

// Barrier WITHOUT vmcnt drain: LDS visibility only. Global loads/stores
// (compiler-generated, lifetimes compiler-tracked) stay in flight across it.
#define LGKM_BAR()                                                    \
  do { asm volatile("s_waitcnt lgkmcnt(0)" ::: "memory");             \
       __builtin_amdgcn_sched_barrier(0);                             \
       __builtin_amdgcn_s_barrier();                                  \
       __builtin_amdgcn_sched_barrier(0); } while (0)

// One tile. VC holds tile kk's coop-linear pieces; VN receives tile kk+1's.
// All global traffic coop-linear: 64 lanes x 16 B = one contiguous aligned
// 1 KB segment per wave instruction.
#define TILE_BODY(VC, VN, kk)                                               \
  {                                                                         \
    const size_t tb = bbase + (size_t)(kk) * TT * F_DIM;                    \
    /* P0: issue next tile's coop loads FIRST (VN is dead; deepest overlap)*/\
    if ((kk) + 1 < NTILE) {                                                 \
      _Pragma("unroll")                                                     \
      for (int r = 0; r < NPC; ++r)                                         \
        VN[r] = *(const f32x4*)(x + tb + (size_t)TT * F_DIM                 \
                                + (size_t)tid * 4 + (size_t)r * 2560);      \
    }                                                                       \
    /* P1: coop-linear pieces -> image (row t = r*NC + c) */                \
    _Pragma("unroll")                                                       \
    for (int r = 0; r < NPC; ++r)                                           \
      *(f32x4*)&s_img[(r * NC + c) * ROWF + g * 4] = VC[r];                 \
    LGKM_BAR();                                                             \
    /* P2: chunk-layout reads; pass-1; summaries */                         \
    f32x4 vX[LTC];                                                          \
    _Pragma("unroll")                                                       \
    for (int j = 0; j < LTC; ++j)                                           \
      vX[j] = *(const f32x4*)&s_img[(LTC * c + j) * ROWF + g * 4];          \
    f32x4 m = 0.f, sp = 0.f, su = 0.f;                                      \
    _Pragma("unroll")                                                       \
    for (int j = 0; j < LTC; ++j) {                                         \
      f32x4 xi = vX[j];                                                     \
      m = ALPHA * m + ONE_M * xi;                                           \
      f32x4 u = xi - m;                                                     \
      sp = ALPHA * sp + ONE_M * (u * u);                                    \
      su = su + u;                                                          \
    }                                                                       \
    *(f32x4*)&s_m [c * F_DIM + g * 4] = m;                                  \
    *(f32x4*)&s_sp[c * F_DIM + g * 4] = sp;                                 \
    *(f32x4*)&s_su[c * F_DIM + g * 4] = su;                                 \
    LGKM_BAR();                                                             \
    /* P3: combine — serial chain over NC chunks, wave-0 threads 0..63 */   \
    if (tid < F_DIM) {                                                      \
      float mu = cmu, var = cvar;                                           \
      for (int cc = 0; cc < NC; ++cc) {                                     \
        float mm = s_m [cc * F_DIM + tid];                                  \
        float pp = s_sp[cc * F_DIM + tid];                                  \
        float uu = s_su[cc * F_DIM + tid];                                  \
        s_m [cc * F_DIM + tid] = mu;          /* entering state */          \
        s_sp[cc * F_DIM + tid] = var;                                       \
        float mun = AL * mu + mm;                                           \
        var = AL * var + pp + (C2 * uu) * mu + RR * mu * mu;                \
        mu = mun;                                                           \
      }                                                                     \
      cmu = mu; cvar = var;                                                 \
    }                                                                       \
    LGKM_BAR();                                                             \
    /* P4: entering state; pass-2 replay; output into image (chunk rows) */ \
    f32x4 mu2  = *(const f32x4*)&s_m [c * F_DIM + g * 4];                   \
    f32x4 var2 = *(const f32x4*)&s_sp[c * F_DIM + g * 4];                   \
    _Pragma("unroll")                                                       \
    for (int j = 0; j < LTC; ++j) {                                         \
      f32x4 xi = vX[j];                                                     \
      mu2 = ALPHA * mu2 + ONE_M * xi;                                       \
      f32x4 d = xi - mu2;                                                   \
      var2 = ALPHA * var2 + ONE_M * (d * d);                                \
      f32x4 o;                                                              \
      o[0] = d[0] * __builtin_amdgcn_rsqf(var2[0]);                         \
      o[1] = d[1] * __builtin_amdgcn_rsqf(var2[1]);                         \
      o[2] = d[2] * __builtin_amdgcn_rsqf(var2[2]);                         \
      o[3] = d[3] * __builtin_amdgcn_rsqf(var2[3]);                         \
      *(f32x4*)&s_img[(LTC * c + j) * ROWF + g * 4] = o;                    \
    }                                                                       \
    LGKM_BAR();                                                             \
    /* P5: coop-linear read-back + contiguous 1KB-per-wave stores */        \
    _Pragma("unroll")                                                       \
    for (int r = 0; r < NPC; ++r) {                                         \
      f32x4 oc = *(const f32x4*)&s_img[(r * NC + c) * ROWF + g * 4];        \
      *(f32x4*)(out + tb + (size_t)tid * 4 + (size_t)r * 2560) = oc;        \
    }                                                                       \
    LGKM_BAR();  /* image reads done before next tile overwrites */         \
  }

// Exact chunked scan per (b,f):
//   mu_L  = a^L mu_0 + m_L
//   var_L = a^L var_0 + SP + c2*SU*mu_0 + R*mu_0^2   (L = LTC = 10)
// x read from HBM exactly once. Padded-row LDS image transposes
// coop-linear <-> chunk layout both directions: every global wave
// instruction is one contiguous aligned 1 KB segment.
__global__ __launch_bounds__(NTHREADS, 2)
void erbnorm_kernel(const float* __restrict__ x, float* __restrict__ out, float aL) {
    const int b   = blockIdx.x;
    const int tid = threadIdx.x;
    const int c   = tid >> 4;          // chunk 0..39 (== coop row sub-index)
    const int g   = tid & 15;          // float4 group 0..15

    const float AL = aL;
    const float C2 = -2.f * ONE_M * aL;        // -2(1-a)a^L
    const float RR = ALPHA * aL * (1.f - aL);  // a^(L+1)(1-a^L)

    __shared__ __align__(16) float s_img[TT * ROWF];          // 108,800 B
    __shared__ float s_m [NC * F_DIM];                        //  10,240 B
    __shared__ float s_sp[NC * F_DIM];                        //  10,240 B
    __shared__ float s_su[NC * F_DIM];                        //  10,240 B

    const size_t bbase = (size_t)b * T_LEN * F_DIM;

    // combine-chain state (meaningful for tid < 64)
    float cmu  = -60.f + (float)tid * (-30.f / 63.f);
    float cvar = 1600.f;

    f32x4 vA[NPC], vB[NPC];
    // prologue: tile 0, coop-linear
#pragma unroll
    for (int r = 0; r < NPC; ++r)
        vA[r] = *(const f32x4*)(x + bbase + (size_t)tid * 4 + (size_t)r * 2560);

    for (int k2 = 0; k2 < NTILE; k2 += 2) {    // 5 clean pairs
        TILE_BODY(vA, vB, k2);
        TILE_BODY(vB, vA, k2 + 1);
    }
}

extern "C" void kernel_launch(void* const* d_in, const int* in_sizes, int n_in,
                              void* d_out, int out_size, void* d_ws, size_t ws_size,
                              hipStream_t stream) {
    const float* x = (const float*)d_in[0];
    float* out = (float*)d_out;
    const float aL = (float)pow(0.99, (double)LTC);  // a^10
    hipLaunchKernelGGL(erbnorm_kernel, dim3(256), dim3(NTHREADS), 0, stream,
                       x, out, aL);
}

// Round 13
// 144.190 us; speedup vs baseline: 1.3230x; 1.3230x over previous
//
#include <hip/hip_runtime.h>
#include <math.h>

#define ALPHA   0.99f
#define ONE_M   0.01f     // 1 - ALPHA
#define T_LEN   4000
#define F_DIM   64
#define TT      160       // time rows per tile
#define NTILE   25        // T_LEN / TT
#define LTC     5         // chunk length (rows per chunk)
#define NC      32        // chunks per tile (global, across 8 waves)
#define NPC     5         // coop pieces per thread
#define NTHREADS 512      // 8 waves
#define ROWF    68        // slab row stride in floats (272 B)
#define SLABF   (20 * ROWF)   // 1360 floats per wave-private slab

typedef float f32x4 __attribute__((ext_vector_type(4)));

// Block barrier WITHOUT vmcnt drain: LDS visibility only; global loads/stores
// stay in flight across it.
#define LGKM_BAR()                                                    \
  do { asm volatile("s_waitcnt lgkmcnt(0)" ::: "memory");             \
       __builtin_amdgcn_sched_barrier(0);                             \
       __builtin_amdgcn_s_barrier();                                  \
       __builtin_amdgcn_sched_barrier(0); } while (0)

// INTRA-WAVE LDS fence (no s_barrier): orders cross-lane ds_write->ds_read
// within the wave, which the compiler's per-thread alias analysis cannot
// see (R12 bug: P2's reads of other lanes' P1 writes got hoisted).
#define WAVE_FENCE()                                                  \
  do { asm volatile("s_waitcnt lgkmcnt(0)" ::: "memory");             \
       __builtin_amdgcn_sched_barrier(0); } while (0)

// One tile. VC = this tile's coop pieces (loaded); VN receives tile kk+1.
// Wave w owns tile rows [20w, 20w+20) == chunks 4w..4w+3: the transpose
// slab is wave-private; summary slots are per-chunk => wave-disjoint.
// Only 2 block barriers per tile (around the cross-wave combine).
#define TILE_BODY(VC, VN, kk)                                               \
  {                                                                         \
    const size_t tb = bbase + (size_t)(kk) * TT * F_DIM;                    \
    /* P0: issue next tile's coop loads first (VN dead; deepest overlap) */ \
    if ((kk) + 1 < NTILE) {                                                 \
      _Pragma("unroll")                                                     \
      for (int r = 0; r < NPC; ++r)                                         \
        VN[r] = *(const f32x4*)(x + tb + (size_t)TT * F_DIM + woff          \
                                + (size_t)r * 256 + (size_t)lw * 4);        \
    }                                                                       \
    /* P1: coop pieces -> own slab (slab row 4r + cl) */                    \
    _Pragma("unroll")                                                       \
    for (int r = 0; r < NPC; ++r)                                           \
      *(f32x4*)&slab[(4 * r + cl) * ROWF + g * 4] = VC[r];                  \
    WAVE_FENCE();   /* cross-lane RAW: P1 writes -> P2 reads */             \
    /* P2: chunk-layout reads (rows 5*cl+j of own slab); pass-1; summary */ \
    f32x4 vX[LTC];                                                          \
    _Pragma("unroll")                                                       \
    for (int j = 0; j < LTC; ++j)                                           \
      vX[j] = *(const f32x4*)&slab[(LTC * cl + j) * ROWF + g * 4];          \
    f32x4 m = 0.f, sp = 0.f, su = 0.f;                                      \
    _Pragma("unroll")                                                       \
    for (int j = 0; j < LTC; ++j) {                                         \
      f32x4 xi = vX[j];                                                     \
      m = ALPHA * m + ONE_M * xi;                                           \
      f32x4 u = xi - m;                                                     \
      sp = ALPHA * sp + ONE_M * (u * u);                                    \
      su = su + u;                                                          \
    }                                                                       \
    *(f32x4*)&s_m [c * F_DIM + g * 4] = m;                                  \
    *(f32x4*)&s_sp[c * F_DIM + g * 4] = sp;                                 \
    *(f32x4*)&s_su[c * F_DIM + g * 4] = su;                                 \
    LGKM_BAR();   /* BAR1: all summaries visible */                         \
    /* P3: combine — serial chain over NC chunks, wave-0 threads 0..63 */   \
    if (tid < F_DIM) {                                                      \
      float mu = cmu, var = cvar;                                           \
      for (int cc = 0; cc < NC; ++cc) {                                     \
        float mm = s_m [cc * F_DIM + tid];                                  \
        float pp = s_sp[cc * F_DIM + tid];                                  \
        float uu = s_su[cc * F_DIM + tid];                                  \
        s_m [cc * F_DIM + tid] = mu;          /* entering state */          \
        s_sp[cc * F_DIM + tid] = var;                                       \
        float mun = AL * mu + mm;                                           \
        var = AL * var + pp + (C2 * uu) * mu + RR * mu * mu;                \
        mu = mun;                                                           \
      }                                                                     \
      cmu = mu; cvar = var;                                                 \
    }                                                                       \
    LGKM_BAR();   /* BAR2: entering states visible */                       \
    /* P4: entering state; pass-2 replay; output -> own slab (chunk rows)*/ \
    f32x4 mu2  = *(const f32x4*)&s_m [c * F_DIM + g * 4];                   \
    f32x4 var2 = *(const f32x4*)&s_sp[c * F_DIM + g * 4];                   \
    _Pragma("unroll")                                                       \
    for (int j = 0; j < LTC; ++j) {                                         \
      f32x4 xi = vX[j];                                                     \
      mu2 = ALPHA * mu2 + ONE_M * xi;                                       \
      f32x4 d = xi - mu2;                                                   \
      var2 = ALPHA * var2 + ONE_M * (d * d);                                \
      f32x4 o;                                                              \
      o[0] = d[0] * __builtin_amdgcn_rsqf(var2[0]);                         \
      o[1] = d[1] * __builtin_amdgcn_rsqf(var2[1]);                         \
      o[2] = d[2] * __builtin_amdgcn_rsqf(var2[2]);                         \
      o[3] = d[3] * __builtin_amdgcn_rsqf(var2[3]);                         \
      *(f32x4*)&slab[(LTC * cl + j) * ROWF + g * 4] = o;                    \
    }                                                                       \
    WAVE_FENCE();   /* cross-lane RAW: P4 writes -> P5 reads */             \
    /* P5: coop read-back from own slab + contiguous 1KB-per-wave stores */ \
    _Pragma("unroll")                                                       \
    for (int r = 0; r < NPC; ++r) {                                         \
      f32x4 oc = *(const f32x4*)&slab[(4 * r + cl) * ROWF + g * 4];         \
      *(f32x4*)(out + tb + woff + (size_t)r * 256 + (size_t)lw * 4) = oc;   \
    }                                                                       \
    WAVE_FENCE();   /* P5 reads done before next tile's P1 overwrites */    \
  }

// Exact chunked scan per (b,f):
//   mu_L  = a^L mu_0 + m_L
//   var_L = a^L var_0 + SP + c2*SU*mu_0 + R*mu_0^2   (L = LTC = 5)
// x read from HBM exactly once; every global wave instruction is one
// contiguous aligned 1 KB segment (wave-private 20-row slab transposes
// coop-linear <-> chunk layout). 2 block barriers per tile.
__global__ __launch_bounds__(NTHREADS, 4)
void erbnorm_kernel(const float* __restrict__ x, float* __restrict__ out, float aL) {
    const int b   = blockIdx.x;
    const int tid = threadIdx.x;
    const int w   = tid >> 6;          // wave 0..7
    const int lw  = tid & 63;          // lane in wave
    const int c   = tid >> 4;          // global chunk 0..31 (= 4w + cl)
    const int cl  = (tid >> 4) & 3;    // chunk-local within wave
    const int g   = tid & 15;          // float4 group 0..15
    const size_t woff = (size_t)w * 1280;   // wave's float offset in tile

    const float AL = aL;
    const float C2 = -2.f * ONE_M * aL;        // -2(1-a)a^L
    const float RR = ALPHA * aL * (1.f - aL);  // a^(L+1)(1-a^L)

    __shared__ __align__(16) float lds_img[8 * SLABF];        // 43,520 B
    __shared__ float s_m [NC * F_DIM];                        //  8,192 B
    __shared__ float s_sp[NC * F_DIM];                        //  8,192 B
    __shared__ float s_su[NC * F_DIM];                        //  8,192 B
    float* slab = &lds_img[w * SLABF];

    const size_t bbase = (size_t)b * T_LEN * F_DIM;

    // combine-chain state (meaningful for tid < 64)
    float cmu  = -60.f + (float)tid * (-30.f / 63.f);
    float cvar = 1600.f;

    f32x4 vA[NPC], vB[NPC];
    // prologue: tile 0, coop-linear (wave-private 20-row block)
#pragma unroll
    for (int r = 0; r < NPC; ++r)
        vA[r] = *(const f32x4*)(x + bbase + woff + (size_t)r * 256 + (size_t)lw * 4);

    for (int k2 = 0; k2 < NTILE - 1; k2 += 2) {   // 12 pairs: tiles 0..23
        TILE_BODY(vA, vB, k2);
        TILE_BODY(vB, vA, k2 + 1);
    }
    TILE_BODY(vA, vB, NTILE - 1);                 // tail tile 24 (no prefetch)
}

extern "C" void kernel_launch(void* const* d_in, const int* in_sizes, int n_in,
                              void* d_out, int out_size, void* d_ws, size_t ws_size,
                              hipStream_t stream) {
    const float* x = (const float*)d_in[0];
    float* out = (float*)d_out;
    const float aL = (float)pow(0.99, (double)LTC);  // a^5
    hipLaunchKernelGGL(erbnorm_kernel, dim3(256), dim3(NTHREADS), 0, stream,
                       x, out, aL);
}

// Round 14
// 114.815 us; speedup vs baseline: 1.6615x; 1.2558x over previous
//
#include <hip/hip_runtime.h>
#include <math.h>

#define ALPHA   0.99f
#define ONE_M   0.01f     // 1 - ALPHA
#define T_LEN   4000
#define F_DIM   64
#define TT      160       // time rows per tile
#define NTILE   25        // T_LEN / TT
#define LTC     5         // chunk length (rows per chunk)
#define NC      32        // chunks per tile (global, across 8 waves)
#define NPC     5         // coop pieces per thread
#define NTHREADS 512      // 8 waves
#define ROWF    68        // slab row stride in floats (272 B)
#define SLABF   (20 * ROWF)   // 1360 floats per wave-private slab

typedef float f32x4 __attribute__((ext_vector_type(4)));

// Block barrier WITHOUT vmcnt drain: LDS visibility only; global loads/stores
// stay in flight across it.
#define LGKM_BAR()                                                    \
  do { asm volatile("s_waitcnt lgkmcnt(0)" ::: "memory");             \
       __builtin_amdgcn_sched_barrier(0);                             \
       __builtin_amdgcn_s_barrier();                                  \
       __builtin_amdgcn_sched_barrier(0); } while (0)

// Intra-wave LDS fence (no s_barrier): orders cross-lane ds_write->ds_read
// within the wave, invisible to per-thread alias analysis (R12 lesson).
#define WAVE_FENCE()                                                  \
  do { asm volatile("s_waitcnt lgkmcnt(0)" ::: "memory");             \
       __builtin_amdgcn_sched_barrier(0); } while (0)

// One tile. VC = this tile's coop pieces (already loaded); VN receives
// tile kk+1. Wave w owns tile rows [20w,20w+20) == chunks 4w..4w+3: the
// transpose slab is wave-private. NO vX register copy: after P1 the tile
// lives in the slab; P4 re-reads its rows and writes o IN PLACE (per-lane
// same address; rows 5cl+j disjoint across cl). Live set stays ~55 VGPR
// -> no spills at the (512,4) 64-VGPR cap (R13's 123MB scratch WRITE).
#define TILE_BODY(VC, VN, kk)                                               \
  {                                                                         \
    const size_t tb = bbase + (size_t)(kk) * TT * F_DIM;                    \
    /* P0: issue next tile's coop loads first (VN dead; deepest overlap) */ \
    if ((kk) + 1 < NTILE) {                                                 \
      _Pragma("unroll")                                                     \
      for (int r = 0; r < NPC; ++r)                                         \
        VN[r] = *(const f32x4*)(x + tb + (size_t)TT * F_DIM + woff          \
                                + (size_t)r * 256 + (size_t)lw * 4);        \
    }                                                                       \
    /* P1: coop pieces -> own slab (slab row 4r + cl); VC dead after */     \
    _Pragma("unroll")                                                       \
    for (int r = 0; r < NPC; ++r)                                           \
      *(f32x4*)&slab[(4 * r + cl) * ROWF + g * 4] = VC[r];                  \
    WAVE_FENCE();   /* cross-lane RAW: P1 writes -> P2 reads */             \
    /* P2: chunk-layout reads (rows 5cl+j); pass-1 sums; summaries */       \
    {                                                                       \
      f32x4 m = 0.f, sp = 0.f, su = 0.f;                                    \
      _Pragma("unroll")                                                     \
      for (int j = 0; j < LTC; ++j) {                                       \
        f32x4 xi = *(const f32x4*)&slab[(LTC * cl + j) * ROWF + g * 4];     \
        m = ALPHA * m + ONE_M * xi;                                         \
        f32x4 u = xi - m;                                                   \
        sp = ALPHA * sp + ONE_M * (u * u);                                  \
        su = su + u;                                                        \
      }                                                                     \
      *(f32x4*)&s_m [c * F_DIM + g * 4] = m;                                \
      *(f32x4*)&s_sp[c * F_DIM + g * 4] = sp;                               \
      *(f32x4*)&s_su[c * F_DIM + g * 4] = su;                               \
    }                                                                       \
    LGKM_BAR();   /* BAR1: all summaries visible */                         \
    /* P3: combine — serial chain over NC chunks, wave-0 threads 0..63 */   \
    if (tid < F_DIM) {                                                      \
      float mu = cmu, var = cvar;                                           \
      for (int cc = 0; cc < NC; ++cc) {                                     \
        float mm = s_m [cc * F_DIM + tid];                                  \
        float pp = s_sp[cc * F_DIM + tid];                                  \
        float uu = s_su[cc * F_DIM + tid];                                  \
        s_m [cc * F_DIM + tid] = mu;          /* entering state */          \
        s_sp[cc * F_DIM + tid] = var;                                       \
        float mun = AL * mu + mm;                                           \
        var = AL * var + pp + (C2 * uu) * mu + RR * mu * mu;                \
        mu = mun;                                                           \
      }                                                                     \
      cmu = mu; cvar = var;                                                 \
    }                                                                       \
    LGKM_BAR();   /* BAR2: entering states visible; WAR vs next summaries */\
    /* P4: entering state; re-read rows 5cl+j; pass-2; write o IN PLACE */  \
    {                                                                       \
      f32x4 mu2  = *(const f32x4*)&s_m [c * F_DIM + g * 4];                 \
      f32x4 var2 = *(const f32x4*)&s_sp[c * F_DIM + g * 4];                 \
      _Pragma("unroll")                                                     \
      for (int j = 0; j < LTC; ++j) {                                       \
        float* rowp = &slab[(LTC * cl + j) * ROWF + g * 4];                 \
        f32x4 xi = *(const f32x4*)rowp;                                     \
        mu2 = ALPHA * mu2 + ONE_M * xi;                                     \
        f32x4 d = xi - mu2;                                                 \
        var2 = ALPHA * var2 + ONE_M * (d * d);                              \
        f32x4 o;                                                            \
        o[0] = d[0] * __builtin_amdgcn_rsqf(var2[0]);                       \
        o[1] = d[1] * __builtin_amdgcn_rsqf(var2[1]);                       \
        o[2] = d[2] * __builtin_amdgcn_rsqf(var2[2]);                       \
        o[3] = d[3] * __builtin_amdgcn_rsqf(var2[3]);                       \
        *(f32x4*)rowp = o;                                                  \
      }                                                                     \
    }                                                                       \
    WAVE_FENCE();   /* cross-lane RAW: P4 writes -> P5 reads */             \
    /* P5: coop read-back from own slab + contiguous 1KB-per-wave stores */ \
    _Pragma("unroll")                                                       \
    for (int r = 0; r < NPC; ++r) {                                         \
      f32x4 oc = *(const f32x4*)&slab[(4 * r + cl) * ROWF + g * 4];         \
      *(f32x4*)(out + tb + woff + (size_t)r * 256 + (size_t)lw * 4) = oc;   \
    }                                                                       \
    WAVE_FENCE();   /* P5 reads done before next tile's P1 overwrites */    \
  }

// Exact chunked scan per (b,f):
//   mu_L  = a^L mu_0 + m_L
//   var_L = a^L var_0 + SP + c2*SU*mu_0 + R*mu_0^2   (L = LTC = 5)
// x read from HBM exactly once; every global wave instruction is one
// contiguous aligned 1 KB segment (wave-private 20-row slab transposes
// coop-linear <-> chunk layout). 2 block barriers per tile.
__global__ __launch_bounds__(NTHREADS, 4)
void erbnorm_kernel(const float* __restrict__ x, float* __restrict__ out, float aL) {
    const int b   = blockIdx.x;
    const int tid = threadIdx.x;
    const int w   = tid >> 6;          // wave 0..7
    const int lw  = tid & 63;          // lane in wave
    const int c   = tid >> 4;          // global chunk 0..31 (= 4w + cl)
    const int cl  = (tid >> 4) & 3;    // chunk-local within wave
    const int g   = tid & 15;          // float4 group 0..15
    const size_t woff = (size_t)w * 1280;   // wave's float offset in tile

    const float AL = aL;
    const float C2 = -2.f * ONE_M * aL;        // -2(1-a)a^L
    const float RR = ALPHA * aL * (1.f - aL);  // a^(L+1)(1-a^L)

    __shared__ __align__(16) float lds_img[8 * SLABF];        // 43,520 B
    __shared__ float s_m [NC * F_DIM];                        //  8,192 B
    __shared__ float s_sp[NC * F_DIM];                        //  8,192 B
    __shared__ float s_su[NC * F_DIM];                        //  8,192 B
    float* slab = &lds_img[w * SLABF];

    const size_t bbase = (size_t)b * T_LEN * F_DIM;

    // combine-chain state (meaningful for tid < 64)
    float cmu  = -60.f + (float)tid * (-30.f / 63.f);
    float cvar = 1600.f;

    f32x4 vA[NPC], vB[NPC];
    // prologue: tile 0, coop-linear (wave-private 20-row block)
#pragma unroll
    for (int r = 0; r < NPC; ++r)
        vA[r] = *(const f32x4*)(x + bbase + woff + (size_t)r * 256 + (size_t)lw * 4);

    for (int k2 = 0; k2 < NTILE - 1; k2 += 2) {   // 12 pairs: tiles 0..23
        TILE_BODY(vA, vB, k2);
        TILE_BODY(vB, vA, k2 + 1);
    }
    TILE_BODY(vA, vB, NTILE - 1);                 // tail tile 24 (no prefetch)
}

extern "C" void kernel_launch(void* const* d_in, const int* in_sizes, int n_in,
                              void* d_out, int out_size, void* d_ws, size_t ws_size,
                              hipStream_t stream) {
    const float* x = (const float*)d_in[0];
    float* out = (float*)d_out;
    const float aL = (float)pow(0.99, (double)LTC);  // a^5
    hipLaunchKernelGGL(erbnorm_kernel, dim3(256), dim3(NTHREADS), 0, stream,
                       x, out, aL);
}

// Round 15
// 112.184 us; speedup vs baseline: 1.7004x; 1.0235x over previous
//
#include <hip/hip_runtime.h>
#include <math.h>

#define ALPHA   0.99f
#define ONE_M   0.01f     // 1 - ALPHA
#define T_LEN   4000
#define F_DIM   64
#define TT      160       // time rows per tile
#define NTILE   25        // T_LEN / TT
#define LTC     5         // chunk length (rows per chunk)
#define NC      32        // chunks per tile (global, across 8 waves)
#define NPC     5         // coop pieces per thread
#define NTHREADS 512      // 8 waves
#define ROWF    68        // slab row stride in floats (272 B)
#define SLABF   (20 * ROWF)   // 1360 floats per wave-private slab

typedef float f32x4 __attribute__((ext_vector_type(4)));

// Block barrier WITHOUT vmcnt drain: LDS visibility only; global loads/stores
// stay in flight across it.
#define LGKM_BAR()                                                    \
  do { asm volatile("s_waitcnt lgkmcnt(0)" ::: "memory");             \
       __builtin_amdgcn_sched_barrier(0);                             \
       __builtin_amdgcn_s_barrier();                                  \
       __builtin_amdgcn_sched_barrier(0); } while (0)

// Intra-wave LDS fence (no s_barrier): orders cross-lane ds_write->ds_read
// within the wave, invisible to per-thread alias analysis (R12 lesson).
#define WAVE_FENCE()                                                  \
  do { asm volatile("s_waitcnt lgkmcnt(0)" ::: "memory");             \
       __builtin_amdgcn_sched_barrier(0); } while (0)

// One tile. VC = this tile's coop pieces (already loaded); VN receives
// tile kk+1. Wave w owns tile rows [20w,20w+20) == chunks 4w..4w+3: the
// transpose slab is wave-private. vX keeps the chunk rows in registers
// across the combine (no P4 slab re-read); grid=256 -> 1 block/CU always,
// so __launch_bounds__(512,2) (256-VGPR cap) costs nothing and kills the
// R13 spills (123 MB scratch WRITE at the 64-VGPR cap).
#define TILE_BODY(VC, VN, kk)                                               \
  {                                                                         \
    const size_t tb = bbase + (size_t)(kk) * TT * F_DIM;                    \
    /* P0: issue next tile's coop loads first (VN dead; deepest overlap) */ \
    if ((kk) + 1 < NTILE) {                                                 \
      _Pragma("unroll")                                                     \
      for (int r = 0; r < NPC; ++r)                                         \
        VN[r] = *(const f32x4*)(x + tb + (size_t)TT * F_DIM + woff          \
                                + (size_t)r * 256 + (size_t)lw * 4);        \
    }                                                                       \
    /* P1: coop pieces -> own slab (slab row 4r + cl); VC dead after */     \
    _Pragma("unroll")                                                       \
    for (int r = 0; r < NPC; ++r)                                           \
      *(f32x4*)&slab[(4 * r + cl) * ROWF + g * 4] = VC[r];                  \
    WAVE_FENCE();   /* cross-lane RAW: P1 writes -> P2 reads */             \
    /* P2: chunk-layout reads into vX; pass-1 sums; summaries */            \
    f32x4 vX[LTC];                                                          \
    {                                                                       \
      f32x4 m = 0.f, sp = 0.f, su = 0.f;                                    \
      _Pragma("unroll")                                                     \
      for (int j = 0; j < LTC; ++j) {                                       \
        vX[j] = *(const f32x4*)&slab[(LTC * cl + j) * ROWF + g * 4];        \
        f32x4 xi = vX[j];                                                   \
        m = ALPHA * m + ONE_M * xi;                                         \
        f32x4 u = xi - m;                                                   \
        sp = ALPHA * sp + ONE_M * (u * u);                                  \
        su = su + u;                                                        \
      }                                                                     \
      *(f32x4*)&s_m [c * F_DIM + g * 4] = m;                                \
      *(f32x4*)&s_sp[c * F_DIM + g * 4] = sp;                               \
      *(f32x4*)&s_su[c * F_DIM + g * 4] = su;                               \
    }                                                                       \
    LGKM_BAR();   /* BAR1: all summaries visible */                         \
    /* P3: combine — serial chain over NC chunks, wave-0 threads 0..63 */   \
    if (tid < F_DIM) {                                                      \
      float mu = cmu, var = cvar;                                           \
      for (int cc = 0; cc < NC; ++cc) {                                     \
        float mm = s_m [cc * F_DIM + tid];                                  \
        float pp = s_sp[cc * F_DIM + tid];                                  \
        float uu = s_su[cc * F_DIM + tid];                                  \
        s_m [cc * F_DIM + tid] = mu;          /* entering state */          \
        s_sp[cc * F_DIM + tid] = var;                                       \
        float mun = AL * mu + mm;                                           \
        var = AL * var + pp + (C2 * uu) * mu + RR * mu * mu;                \
        mu = mun;                                                           \
      }                                                                     \
      cmu = mu; cvar = var;                                                 \
    }                                                                       \
    LGKM_BAR();   /* BAR2: entering states visible; WAR vs next summaries */\
    /* P4: entering state; pass-2 from vX registers; o -> slab chunk rows */\
    {                                                                       \
      f32x4 mu2  = *(const f32x4*)&s_m [c * F_DIM + g * 4];                 \
      f32x4 var2 = *(const f32x4*)&s_sp[c * F_DIM + g * 4];                 \
      _Pragma("unroll")                                                     \
      for (int j = 0; j < LTC; ++j) {                                       \
        f32x4 xi = vX[j];                                                   \
        mu2 = ALPHA * mu2 + ONE_M * xi;                                     \
        f32x4 d = xi - mu2;                                                 \
        var2 = ALPHA * var2 + ONE_M * (d * d);                              \
        f32x4 o;                                                            \
        o[0] = d[0] * __builtin_amdgcn_rsqf(var2[0]);                       \
        o[1] = d[1] * __builtin_amdgcn_rsqf(var2[1]);                       \
        o[2] = d[2] * __builtin_amdgcn_rsqf(var2[2]);                       \
        o[3] = d[3] * __builtin_amdgcn_rsqf(var2[3]);                       \
        *(f32x4*)&slab[(LTC * cl + j) * ROWF + g * 4] = o;                  \
      }                                                                     \
    }                                                                       \
    WAVE_FENCE();   /* cross-lane RAW: P4 writes -> P5 reads */             \
    /* P5: coop read-back from own slab + contiguous 1KB-per-wave stores */ \
    _Pragma("unroll")                                                       \
    for (int r = 0; r < NPC; ++r) {                                         \
      f32x4 oc = *(const f32x4*)&slab[(4 * r + cl) * ROWF + g * 4];         \
      *(f32x4*)(out + tb + woff + (size_t)r * 256 + (size_t)lw * 4) = oc;   \
    }                                                                       \
    WAVE_FENCE();   /* P5 reads done before next tile's P1 overwrites */    \
  }

// Exact chunked scan per (b,f):
//   mu_L  = a^L mu_0 + m_L
//   var_L = a^L var_0 + SP + c2*SU*mu_0 + R*mu_0^2   (L = LTC = 5)
// x read from HBM exactly once; every global wave instruction is one
// contiguous aligned 1 KB segment (wave-private 20-row slab transposes
// coop-linear <-> chunk layout). 2 block barriers per tile.
__global__ __launch_bounds__(NTHREADS, 2)
void erbnorm_kernel(const float* __restrict__ x, float* __restrict__ out, float aL) {
    const int b   = blockIdx.x;
    const int tid = threadIdx.x;
    const int w   = tid >> 6;          // wave 0..7
    const int lw  = tid & 63;          // lane in wave
    const int c   = tid >> 4;          // global chunk 0..31 (= 4w + cl)
    const int cl  = (tid >> 4) & 3;    // chunk-local within wave
    const int g   = tid & 15;          // float4 group 0..15
    const size_t woff = (size_t)w * 1280;   // wave's float offset in tile

    const float AL = aL;
    const float C2 = -2.f * ONE_M * aL;        // -2(1-a)a^L
    const float RR = ALPHA * aL * (1.f - aL);  // a^(L+1)(1-a^L)

    __shared__ __align__(16) float lds_img[8 * SLABF];        // 43,520 B
    __shared__ float s_m [NC * F_DIM];                        //  8,192 B
    __shared__ float s_sp[NC * F_DIM];                        //  8,192 B
    __shared__ float s_su[NC * F_DIM];                        //  8,192 B
    float* slab = &lds_img[w * SLABF];

    const size_t bbase = (size_t)b * T_LEN * F_DIM;

    // combine-chain state (meaningful for tid < 64)
    float cmu  = -60.f + (float)tid * (-30.f / 63.f);
    float cvar = 1600.f;

    f32x4 vA[NPC], vB[NPC];
    // prologue: tile 0, coop-linear (wave-private 20-row block)
#pragma unroll
    for (int r = 0; r < NPC; ++r)
        vA[r] = *(const f32x4*)(x + bbase + woff + (size_t)r * 256 + (size_t)lw * 4);

    for (int k2 = 0; k2 < NTILE - 1; k2 += 2) {   // 12 pairs: tiles 0..23
        TILE_BODY(vA, vB, k2);
        TILE_BODY(vB, vA, k2 + 1);
    }
    TILE_BODY(vA, vB, NTILE - 1);                 // tail tile 24 (no prefetch)
}

extern "C" void kernel_launch(void* const* d_in, const int* in_sizes, int n_in,
                              void* d_out, int out_size, void* d_ws, size_t ws_size,
                              hipStream_t stream) {
    const float* x = (const float*)d_in[0];
    float* out = (float*)d_out;
    const float aL = (float)pow(0.99, (double)LTC);  // a^5
    hipLaunchKernelGGL(erbnorm_kernel, dim3(256), dim3(NTHREADS), 0, stream,
                       x, out, aL);
}

// Round 16
// 107.558 us; speedup vs baseline: 1.7736x; 1.0430x over previous
//
#include <hip/hip_runtime.h>
#include <math.h>

#define ALPHA   0.99f
#define ONE_M   0.01f     // 1 - ALPHA
#define T_LEN   4000
#define F_DIM   64
#define TT      160       // time rows per tile
#define NTILE   25        // T_LEN / TT
#define LTC     5         // chunk length (rows per chunk)
#define NC      32        // chunks per tile (global, across 8 waves)
#define NPC     5         // coop pieces per thread
#define NTHREADS 512      // 8 waves
#define ROWF    68        // slab row stride in floats (272 B)
#define SLABF   (20 * ROWF)   // 1360 floats per wave-private slab

typedef float f32x4 __attribute__((ext_vector_type(4)));

// Block barrier WITHOUT vmcnt drain: LDS visibility only; global loads/stores
// stay in flight across it.
#define LGKM_BAR()                                                    \
  do { asm volatile("s_waitcnt lgkmcnt(0)" ::: "memory");             \
       __builtin_amdgcn_sched_barrier(0);                             \
       __builtin_amdgcn_s_barrier();                                  \
       __builtin_amdgcn_sched_barrier(0); } while (0)

// Intra-wave LDS fence (no s_barrier): orders cross-lane ds_write->ds_read
// within the wave, invisible to per-thread alias analysis (R12 lesson).
#define WAVE_FENCE()                                                  \
  do { asm volatile("s_waitcnt lgkmcnt(0)" ::: "memory");             \
       __builtin_amdgcn_sched_barrier(0); } while (0)

// One tile. VC = this tile's coop pieces (already loaded); VN receives
// tile kk+1. Wave w owns tile rows [20w,20w+20) == chunks 4w..4w+3: the
// transpose slab is wave-private. x is streamed once (nontemporal loads),
// out is write-only (nontemporal stores) -> neither pollutes L2/L3.
#define TILE_BODY(VC, VN, kk)                                               \
  {                                                                         \
    const size_t tb = bbase + (size_t)(kk) * TT * F_DIM;                    \
    /* P0: issue next tile's coop loads first (VN dead; deepest overlap) */ \
    if ((kk) + 1 < NTILE) {                                                 \
      _Pragma("unroll")                                                     \
      for (int r = 0; r < NPC; ++r)                                         \
        VN[r] = __builtin_nontemporal_load(                                 \
            (const f32x4*)(x + tb + (size_t)TT * F_DIM + woff               \
                           + (size_t)r * 256 + (size_t)lw * 4));            \
    }                                                                       \
    /* P1: coop pieces -> own slab (slab row 4r + cl); VC dead after */     \
    _Pragma("unroll")                                                       \
    for (int r = 0; r < NPC; ++r)                                           \
      *(f32x4*)&slab[(4 * r + cl) * ROWF + g * 4] = VC[r];                  \
    WAVE_FENCE();   /* cross-lane RAW: P1 writes -> P2 reads */             \
    /* P2: chunk-layout reads into vX; pass-1 sums; summaries */            \
    f32x4 vX[LTC];                                                          \
    {                                                                       \
      f32x4 m = 0.f, sp = 0.f, su = 0.f;                                    \
      _Pragma("unroll")                                                     \
      for (int j = 0; j < LTC; ++j) {                                       \
        vX[j] = *(const f32x4*)&slab[(LTC * cl + j) * ROWF + g * 4];        \
        f32x4 xi = vX[j];                                                   \
        m = ALPHA * m + ONE_M * xi;                                         \
        f32x4 u = xi - m;                                                   \
        sp = ALPHA * sp + ONE_M * (u * u);                                  \
        su = su + u;                                                        \
      }                                                                     \
      *(f32x4*)&s_m [c * F_DIM + g * 4] = m;                                \
      *(f32x4*)&s_sp[c * F_DIM + g * 4] = sp;                               \
      *(f32x4*)&s_su[c * F_DIM + g * 4] = su;                               \
    }                                                                       \
    LGKM_BAR();   /* BAR1: all summaries visible */                         \
    /* P3: combine — serial chain over NC chunks, wave-0 threads 0..63 */   \
    if (tid < F_DIM) {                                                      \
      float mu = cmu, var = cvar;                                           \
      for (int cc = 0; cc < NC; ++cc) {                                     \
        float mm = s_m [cc * F_DIM + tid];                                  \
        float pp = s_sp[cc * F_DIM + tid];                                  \
        float uu = s_su[cc * F_DIM + tid];                                  \
        s_m [cc * F_DIM + tid] = mu;          /* entering state */          \
        s_sp[cc * F_DIM + tid] = var;                                       \
        float mun = AL * mu + mm;                                           \
        var = AL * var + pp + (C2 * uu) * mu + RR * mu * mu;                \
        mu = mun;                                                           \
      }                                                                     \
      cmu = mu; cvar = var;                                                 \
    }                                                                       \
    LGKM_BAR();   /* BAR2: entering states visible; WAR vs next summaries */\
    /* P4: entering state; pass-2 from vX registers; o -> slab chunk rows */\
    {                                                                       \
      f32x4 mu2  = *(const f32x4*)&s_m [c * F_DIM + g * 4];                 \
      f32x4 var2 = *(const f32x4*)&s_sp[c * F_DIM + g * 4];                 \
      _Pragma("unroll")                                                     \
      for (int j = 0; j < LTC; ++j) {                                       \
        f32x4 xi = vX[j];                                                   \
        mu2 = ALPHA * mu2 + ONE_M * xi;                                     \
        f32x4 d = xi - mu2;                                                 \
        var2 = ALPHA * var2 + ONE_M * (d * d);                              \
        f32x4 o;                                                            \
        o[0] = d[0] * __builtin_amdgcn_rsqf(var2[0]);                       \
        o[1] = d[1] * __builtin_amdgcn_rsqf(var2[1]);                       \
        o[2] = d[2] * __builtin_amdgcn_rsqf(var2[2]);                       \
        o[3] = d[3] * __builtin_amdgcn_rsqf(var2[3]);                       \
        *(f32x4*)&slab[(LTC * cl + j) * ROWF + g * 4] = o;                  \
      }                                                                     \
    }                                                                       \
    WAVE_FENCE();   /* cross-lane RAW: P4 writes -> P5 reads */             \
    /* P5: coop read-back from own slab + contiguous 1KB nontemporal stores*/\
    _Pragma("unroll")                                                       \
    for (int r = 0; r < NPC; ++r) {                                         \
      f32x4 oc = *(const f32x4*)&slab[(4 * r + cl) * ROWF + g * 4];         \
      __builtin_nontemporal_store(oc,                                       \
          (f32x4*)(out + tb + woff + (size_t)r * 256 + (size_t)lw * 4));    \
    }                                                                       \
    WAVE_FENCE();   /* P5 reads done before next tile's P1 overwrites */    \
  }

// Exact chunked scan per (b,f):
//   mu_L  = a^L mu_0 + m_L
//   var_L = a^L var_0 + SP + c2*SU*mu_0 + R*mu_0^2   (L = LTC = 5)
// x read from HBM exactly once; every global wave instruction is one
// contiguous aligned 1 KB segment (wave-private 20-row slab transposes
// coop-linear <-> chunk layout). 2 block barriers per tile.
__global__ __launch_bounds__(NTHREADS, 2)
void erbnorm_kernel(const float* __restrict__ x, float* __restrict__ out, float aL) {
    const int b   = blockIdx.x;
    const int tid = threadIdx.x;
    const int w   = tid >> 6;          // wave 0..7
    const int lw  = tid & 63;          // lane in wave
    const int c   = tid >> 4;          // global chunk 0..31 (= 4w + cl)
    const int cl  = (tid >> 4) & 3;    // chunk-local within wave
    const int g   = tid & 15;          // float4 group 0..15
    const size_t woff = (size_t)w * 1280;   // wave's float offset in tile

    const float AL = aL;
    const float C2 = -2.f * ONE_M * aL;        // -2(1-a)a^L
    const float RR = ALPHA * aL * (1.f - aL);  // a^(L+1)(1-a^L)

    __shared__ __align__(16) float lds_img[8 * SLABF];        // 43,520 B
    __shared__ float s_m [NC * F_DIM];                        //  8,192 B
    __shared__ float s_sp[NC * F_DIM];                        //  8,192 B
    __shared__ float s_su[NC * F_DIM];                        //  8,192 B
    float* slab = &lds_img[w * SLABF];

    const size_t bbase = (size_t)b * T_LEN * F_DIM;

    // combine-chain state (meaningful for tid < 64)
    float cmu  = -60.f + (float)tid * (-30.f / 63.f);
    float cvar = 1600.f;

    f32x4 vA[NPC], vB[NPC];
    // prologue: tile 0, coop-linear (wave-private 20-row block)
#pragma unroll
    for (int r = 0; r < NPC; ++r)
        vA[r] = __builtin_nontemporal_load(
            (const f32x4*)(x + bbase + woff + (size_t)r * 256 + (size_t)lw * 4));

    for (int k2 = 0; k2 < NTILE - 1; k2 += 2) {   // 12 pairs: tiles 0..23
        TILE_BODY(vA, vB, k2);
        TILE_BODY(vB, vA, k2 + 1);
    }
    TILE_BODY(vA, vB, NTILE - 1);                 // tail tile 24 (no prefetch)
}

extern "C" void kernel_launch(void* const* d_in, const int* in_sizes, int n_in,
                              void* d_out, int out_size, void* d_ws, size_t ws_size,
                              hipStream_t stream) {
    const float* x = (const float*)d_in[0];
    float* out = (float*)d_out;
    const float aL = (float)pow(0.99, (double)LTC);  // a^5
    hipLaunchKernelGGL(erbnorm_kernel, dim3(256), dim3(NTHREADS), 0, stream,
                       x, out, aL);
}